// Round 1
// baseline (213.616 us; speedup 1.0000x reference)
//
#include <hip/hip_runtime.h>

#define B_ 8
#define CIN_ 256
#define COUT_ 256

typedef short short8_t __attribute__((ext_vector_type(8)));
typedef float float4_t __attribute__((ext_vector_type(4)));

// ws layout (shorts): dwA [0, DWA_SHORTS) ; xpre [DWA_SHORTS, +XPRE_SHORTS)
// dwA  : [b][tap9][oct32][co256][ci8]                      bf16
// xpre : [b][cb8][h66][col66][chunk4][8]  (chunk = oct ^ ((col>>1)&3))  bf16
#define DWA_SHORTS   (B_ * 9 * 32 * COUT_ * 8)      // 4,718,592
#define XPRE_SHORTS  (B_ * 8 * 66 * 66 * 32)        // 8,921,088

__device__ __forceinline__ unsigned short f2bf(float f) {
    union { float f; unsigned u; } v; v.f = f;
    unsigned u = v.u;
    unsigned r = (u + 0x7fffu + ((u >> 16) & 1u)) >> 16;  // RNE
    return (unsigned short)r;
}

// async global->LDS, 16B per lane. LDS dest must be wave-linear (it is: tid*16).
__device__ __forceinline__ void gload_lds16(const unsigned short* g, unsigned short* l) {
    __builtin_amdgcn_global_load_lds(
        (__attribute__((address_space(1))) void*)(g),
        (__attribute__((address_space(3))) void*)(l), 16, 0, 0);
}

// ---------------------------------------------------------------------------
// K_prep: fused  (blocks 0..63: modulate+demodulate)  (blocks 64..4287: xpre)
// ---------------------------------------------------------------------------
__global__ __launch_bounds__(256) void k_prep(const float* __restrict__ x,
                                              const float* __restrict__ style,
                                              const float* __restrict__ weight,
                                              unsigned short* __restrict__ xpre,
                                              unsigned short* __restrict__ dwA) {
    const int blk = blockIdx.x;
    const int t = threadIdx.x;

    if (blk >= 64) {
        // ---- xpre: x fp32 NCHW -> bf16 [b][cb][h66][col66][swizzled oct] ----
        const int e = blk - 64;                 // (b*8+cb)*66 + h_out
        const int h_out = e % 66;
        const int q2 = e / 66;
        const int cb = q2 & 7, b = q2 >> 3;
        const int h_in = h_out - 1;
        unsigned short* dst_row = xpre + ((size_t)(b * 8 + cb) * 66 + h_out) * 66 * 32;
#pragma unroll
        for (int pass = 0; pass < 2; ++pass) {
            int p = t + pass * 256;
            if (p >= 264) break;
            int w_out = p >> 2, g = p & 3;      // g = source ci-oct (of 4 per pass... 4 octs x 8ci = 32 ci)
            int w_in = w_out - 1;
            short8_t v = (short8_t){0, 0, 0, 0, 0, 0, 0, 0};
            if ((unsigned)h_in < 64u && (unsigned)w_in < 64u) {
                const float* xp = x + (((size_t)(b * CIN_ + cb * 32 + g * 8)) * 64 + h_in) * 64 + w_in;
#pragma unroll
                for (int j = 0; j < 8; ++j) v[j] = (short)f2bf(xp[(size_t)j * 4096]);
            }
            // XOR-swizzle the chunk slot so k_conv's ds_read_b128 is conflict-free
            // while the strip stays a LINEAR global_load_lds copy.
            const int chunk = g ^ ((w_out >> 1) & 3);
            *(short8_t*)(dst_row + (size_t)w_out * 32 + chunk * 8) = v;
        }
        return;
    }

    // ---- modulate+demodulate -> dwA bf16 [b][tap9][oct32][co256][ci8] ----
    // (no LDS: weights read directly; 9-float runs per (co,ci) are L1/L2-served)
    const int co_l = t >> 6;
    const int lane = t & 63;
    const int co = blk * 4 + co_l;

    float wv[4][9];
    float ss[4];
    const float* wp = weight + (size_t)co * 2304;
#pragma unroll
    for (int k = 0; k < 4; ++k) {
        float a = 0.f;
#pragma unroll
        for (int tap = 0; tap < 9; ++tap) {
            float w = wp[(lane + 64 * k) * 9 + tap];
            wv[k][tap] = w;
            a += w * w;
        }
        ss[k] = a;
    }
    float sv[8][4];
#pragma unroll
    for (int b = 0; b < 8; ++b)
#pragma unroll
        for (int k = 0; k < 4; ++k) sv[b][k] = style[b * CIN_ + lane + 64 * k];

    float inv[8];
#pragma unroll
    for (int b = 0; b < 8; ++b) {
        float part = 0.f;
#pragma unroll
        for (int k = 0; k < 4; ++k) part += sv[b][k] * sv[b][k] * ss[k];
#pragma unroll
        for (int off = 32; off > 0; off >>= 1) part += __shfl_xor(part, off, 64);
        inv[b] = 1.0f / sqrtf(part + 1e-8f);
    }

    const size_t base = (size_t)co * 8 + (lane & 7) + (size_t)(lane >> 3) * 2048;
#pragma unroll
    for (int b = 0; b < 8; ++b)
#pragma unroll
        for (int tap = 0; tap < 9; ++tap)
#pragma unroll
            for (int k = 0; k < 4; ++k) {
                size_t addr = ((size_t)(b * 9 + tap) * 32 + k * 8) * 2048 + base;
                dwA[addr] = f2bf(wv[k][tap] * sv[b][k] * inv[b]);
            }
}

// ---------------------------------------------------------------------------
// K_conv: 9 shifted GEMMs. 256 blocks (x=b so XCD=b -> dwA L2-resident),
// 4 waves (2M x 2N), wave tile M=128co x N=64col, acc 8x4.
// x-tile staged via global_load_lds (linear copy of pre-swizzled xpre).
// ---------------------------------------------------------------------------
__global__ __launch_bounds__(256, 1) void k_conv(const unsigned short* __restrict__ xpre,
                                                 const unsigned short* __restrict__ dwA,
                                                 float* __restrict__ out) {
    __shared__ __align__(16) unsigned short xs[2][4 * 66 * 32];  // 2 x 16.9 KB

    const int b = blockIdx.x;        // 0..7  (linear id % 8 -> XCD = b)
    const int rowgrp = blockIdx.y;   // 0..31
    const int tid = threadIdx.x;
    const int lane = tid & 63, wid = tid >> 6;
    const int wave_m = wid >> 1, wave_n = wid & 1;
    const int quad = lane >> 4, l16 = lane & 15;
    const int r0 = rowgrp * 2;
    const int co_base = wave_m * 128;

    float4_t acc[8][4];
#pragma unroll
    for (int mi = 0; mi < 8; ++mi)
#pragma unroll
        for (int ni = 0; ni < 4; ++ni) acc[mi][ni] = (float4_t){0.f, 0.f, 0.f, 0.f};

    const unsigned short* src_base = xpre + (size_t)b * 8 * 66 * 66 * 32;

    // stage 4 rows x 66 cols x 32 ci = 1056 x 16B, linear (xpre is pre-swizzled)
    auto stage = [&](int cb, int buf) {
        const unsigned short* s = src_base + ((size_t)cb * 66 + r0) * 2112;
        unsigned short* d = xs[buf];
#pragma unroll
        for (int k = 0; k < 4; ++k)
            gload_lds16(s + (size_t)(tid + k * 256) * 8, d + (size_t)(tid + k * 256) * 8);
        if (tid < 32)
            gload_lds16(s + (size_t)(tid + 1024) * 8, d + (size_t)(tid + 1024) * 8);
    };

    short8_t abuf[2][8];
    auto loadA = [&](short8_t* dst, int acb, int atap) {
        const unsigned short* Ab = dwA + ((size_t)(b * 9 + atap) * 32 + acb * 4 + quad) * 2048
                                       + (size_t)(co_base + l16) * 8;
#pragma unroll
        for (int mi = 0; mi < 8; ++mi)
            dst[mi] = *(const short8_t*)(Ab + mi * 128);
    };

    short8_t bf[2][4];
    auto readB = [&](short8_t* dst, const unsigned short* xb, int tap) {
        const int dh = tap / 3, dwc = tap % 3;
        const unsigned short* brow = xb + (wave_n + dh) * (66 * 32);
#pragma unroll
        for (int ni = 0; ni < 4; ++ni) {
            const int col = ni * 16 + l16 + dwc;
            dst[ni] = *(const short8_t*)(brow + col * 32 + (quad ^ ((col >> 1) & 3)) * 8);
        }
    };

    // One cb-step: barrier (drains staged loads), issue next stage, 9 taps with
    // A 1-step-ahead (global->reg) and B 1-tap-ahead (lds->reg) double-buffering.
    // PAR is compile-time so every register-array index is static (rule #20).
#define TAP_BLOCK(CBV, PAR)                                                   \
    do {                                                                      \
        const unsigned short* xb_ = xs[(PAR)];                                \
        readB(bf[0], xb_, 0);                                                 \
        _Pragma("unroll")                                                     \
        for (int tap = 0; tap < 9; ++tap) {                                   \
            if (tap < 8) {                                                    \
                loadA(abuf[((PAR) + tap + 1) & 1], (CBV), tap + 1);           \
                readB(bf[(tap + 1) & 1], xb_, tap + 1);                       \
            } else if ((CBV) < 7) {                                           \
                loadA(abuf[((PAR) + 1) & 1], (CBV) + 1, 0);                   \
            }                                                                 \
            const short8_t* ac = abuf[((PAR) + tap) & 1];                     \
            const short8_t* bc = bf[tap & 1];                                 \
            _Pragma("unroll")                                                 \
            for (int mi = 0; mi < 8; ++mi)                                    \
                _Pragma("unroll")                                             \
                for (int ni = 0; ni < 4; ++ni)                                \
                    acc[mi][ni] = __builtin_amdgcn_mfma_f32_16x16x32_bf16(    \
                        ac[mi], bc[ni], acc[mi][ni], 0, 0, 0);                \
        }                                                                     \
    } while (0)

    stage(0, 0);
    loadA(abuf[0], 0, 0);

    for (int cb2 = 0; cb2 < 4; ++cb2) {
        const int cbA = cb2 * 2, cbB = cbA + 1;
        __syncthreads();                 // vmcnt(0) drain: xs[0] for cbA ready
        stage(cbB, 1);                   // cbB <= 7 always
        TAP_BLOCK(cbA, 0);
        __syncthreads();                 // xs[1] for cbB ready
        if (cbB < 7) stage(cbB + 1, 0);
        TAP_BLOCK(cbB, 1);
    }
#undef TAP_BLOCK

    // epilogue: D row = quad*4 + r (co), col = l16 (img col)
    const int orow = r0 + wave_n;
    float* outp = out + ((size_t)b * COUT_ + co_base) * 4096 + (size_t)orow * 64;
#pragma unroll
    for (int mi = 0; mi < 8; ++mi)
#pragma unroll
        for (int ni = 0; ni < 4; ++ni)
#pragma unroll
            for (int r = 0; r < 4; ++r)
                outp[(size_t)(mi * 16 + quad * 4 + r) * 4096 + ni * 16 + l16] = acc[mi][ni][r];
}

extern "C" void kernel_launch(void* const* d_in, const int* in_sizes, int n_in,
                              void* d_out, int out_size, void* d_ws, size_t ws_size,
                              hipStream_t stream) {
    const float* x = (const float*)d_in[0];
    const float* style = (const float*)d_in[1];
    const float* weight = (const float*)d_in[2];
    float* out = (float*)d_out;

    unsigned short* dwA = (unsigned short*)d_ws;
    unsigned short* xpre = dwA + DWA_SHORTS;

    // blocks 0..63 modulate, 64..4287 xpre (64 + 8*8*66)
    k_prep<<<dim3(64 + B_ * 8 * 66), 256, 0, stream>>>(x, style, weight, xpre, dwA);
    // x = b so XCD (= linear_id % 8) = b: per-XCD dwA (1.18 MB) + xpre slice L2-resident
    k_conv<<<dim3(8, 32), 256, 0, stream>>>(xpre, dwA, out);
}

// Round 2
// 124.061 us; speedup vs baseline: 1.7219x; 1.7219x over previous
//
#include <hip/hip_runtime.h>

#define B_ 8
#define CIN_ 256
#define COUT_ 256

typedef short short8_t __attribute__((ext_vector_type(8)));
typedef float float4_t __attribute__((ext_vector_type(4)));

// ws layout (shorts): dwA [0, DWA_SHORTS) ; xpre [DWA_SHORTS, +XPRE_SHORTS)
// dwA  : [b][tap9][oct32][co256][ci8]                      bf16
// xpre : [b][cb8][h66][col66][chunk4][8]  (chunk = oct ^ ((col>>1)&3))  bf16
#define DWA_SHORTS   (B_ * 9 * 32 * COUT_ * 8)      // 4,718,592
#define XPRE_SHORTS  (B_ * 8 * 66 * 66 * 32)        // 8,921,088

__device__ __forceinline__ unsigned short f2bf(float f) {
    union { float f; unsigned u; } v; v.f = f;
    unsigned u = v.u;
    unsigned r = (u + 0x7fffu + ((u >> 16) & 1u)) >> 16;  // RNE
    return (unsigned short)r;
}

// async global->LDS, 16B per lane. LDS dest must be wave-linear (it is: tid*16).
__device__ __forceinline__ void gload_lds16(const unsigned short* g, unsigned short* l) {
    __builtin_amdgcn_global_load_lds(
        (__attribute__((address_space(1))) void*)(g),
        (__attribute__((address_space(3))) void*)(l), 16, 0, 0);
}

// ---------------------------------------------------------------------------
// K_prep: fused  (blocks 0..63: modulate+demodulate)  (blocks 64..4287: xpre)
// ---------------------------------------------------------------------------
__global__ __launch_bounds__(256) void k_prep(const float* __restrict__ x,
                                              const float* __restrict__ style,
                                              const float* __restrict__ weight,
                                              unsigned short* __restrict__ xpre,
                                              unsigned short* __restrict__ dwA) {
    const int blk = blockIdx.x;
    const int t = threadIdx.x;

    if (blk >= 64) {
        // ---- xpre: x fp32 NCHW -> bf16 [b][cb][h66][col66][swizzled chunk] ----
        const int e = blk - 64;                 // (b*8+cb)*66 + h_out
        const int h_out = e % 66;
        const int q2 = e / 66;
        const int cb = q2 & 7, b = q2 >> 3;
        const int h_in = h_out - 1;
        unsigned short* dst_row = xpre + ((size_t)(b * 8 + cb) * 66 + h_out) * 66 * 32;

        if ((unsigned)h_in >= 64u) {            // halo rows: pure zero-fill
            short8_t z = (short8_t){0, 0, 0, 0, 0, 0, 0, 0};
#pragma unroll
            for (int pass = 0; pass < 2; ++pass) {
                int p = t + pass * 256;
                if (p >= 264) break;
                int w_out = p >> 2, g = p & 3;
                int chunk = g ^ ((w_out >> 1) & 3);
                *(short8_t*)(dst_row + (size_t)w_out * 32 + chunk * 8) = z;
            }
            return;
        }

        // load: fully coalesced float4 (each thread: one ci row, 8 w's)
        __shared__ __align__(16) unsigned short xl[64 * 40];  // [w][ci], pad 40
        const int ci_l = t >> 3, w8 = (t & 7) * 8;
        const float* xp = x + (((size_t)(b * CIN_ + cb * 32 + ci_l)) * 64 + h_in) * 64 + w8;
        float4_t v0 = *(const float4_t*)xp;
        float4_t v1 = *(const float4_t*)(xp + 4);
#pragma unroll
        for (int k = 0; k < 4; ++k) xl[(w8 + k) * 40 + ci_l] = f2bf(v0[k]);
#pragma unroll
        for (int k = 0; k < 4; ++k) xl[(w8 + 4 + k) * 40 + ci_l] = f2bf(v1[k]);
        __syncthreads();

        // store: transpose out of LDS, 16B per lane, chunk-swizzled
#pragma unroll
        for (int pass = 0; pass < 2; ++pass) {
            int p = t + pass * 256;
            if (p >= 264) break;
            int w_out = p >> 2, g = p & 3;
            int w_in = w_out - 1;
            short8_t v = (short8_t){0, 0, 0, 0, 0, 0, 0, 0};
            if ((unsigned)w_in < 64u)
                v = *(const short8_t*)(xl + w_in * 40 + g * 8);
            int chunk = g ^ ((w_out >> 1) & 3);
            *(short8_t*)(dst_row + (size_t)w_out * 32 + chunk * 8) = v;
        }
        return;
    }

    // ---- modulate+demodulate -> dwA bf16 [b][tap9][oct32][co256][ci8] ----
    const int co_l = t >> 6;
    const int lane = t & 63;
    const int co = blk * 4 + co_l;

    float wv[4][9];
    float ss[4];
    const float* wp = weight + (size_t)co * 2304;
#pragma unroll
    for (int k = 0; k < 4; ++k) {
        float a = 0.f;
#pragma unroll
        for (int tap = 0; tap < 9; ++tap) {
            float w = wp[(lane + 64 * k) * 9 + tap];
            wv[k][tap] = w;
            a += w * w;
        }
        ss[k] = a;
    }
    float sv[8][4];
#pragma unroll
    for (int b = 0; b < 8; ++b)
#pragma unroll
        for (int k = 0; k < 4; ++k) sv[b][k] = style[b * CIN_ + lane + 64 * k];

    float inv[8];
#pragma unroll
    for (int b = 0; b < 8; ++b) {
        float part = 0.f;
#pragma unroll
        for (int k = 0; k < 4; ++k) part += sv[b][k] * sv[b][k] * ss[k];
#pragma unroll
        for (int off = 32; off > 0; off >>= 1) part += __shfl_xor(part, off, 64);
        inv[b] = 1.0f / sqrtf(part + 1e-8f);
    }

    const size_t base = (size_t)co * 8 + (lane & 7) + (size_t)(lane >> 3) * 2048;
#pragma unroll
    for (int b = 0; b < 8; ++b)
#pragma unroll
        for (int tap = 0; tap < 9; ++tap)
#pragma unroll
            for (int k = 0; k < 4; ++k) {
                size_t addr = ((size_t)(b * 9 + tap) * 32 + k * 8) * 2048 + base;
                dwA[addr] = f2bf(wv[k][tap] * sv[b][k] * inv[b]);
            }
}

// ---------------------------------------------------------------------------
// K_conv: 9 shifted GEMMs. 512 blocks (x=b -> XCD=b, dwA+xpre L2-resident),
// 4 waves (2M x 2N), wave tile M=64co x N=64col, acc 4x4 -> 2 blocks/CU,
// 8 waves/CU. x staged via global_load_lds (linear copy of swizzled xpre),
// one barrier per cb-step, A 2-taps-ahead (3-deep), B 1-tap-ahead (2-deep).
// ---------------------------------------------------------------------------
__global__ __launch_bounds__(256, 2) void k_conv(const unsigned short* __restrict__ xpre,
                                                 const unsigned short* __restrict__ dwA,
                                                 float* __restrict__ out) {
    __shared__ __align__(16) unsigned short xs[2][4 * 66 * 32];  // 2 x 16.9 KB

    const int b = blockIdx.x;        // 0..7  (linear id % 8 -> XCD = b)
    const int rowgrp = blockIdx.y;   // 0..31
    const int co_tile = blockIdx.z;  // 0..1
    const int tid = threadIdx.x;
    const int lane = tid & 63, wid = tid >> 6;
    const int wave_m = wid >> 1, wave_n = wid & 1;
    const int quad = lane >> 4, l16 = lane & 15;
    const int r0 = rowgrp * 2;
    const int co_base = co_tile * 128 + wave_m * 64;

    float4_t acc[4][4];
#pragma unroll
    for (int mi = 0; mi < 4; ++mi)
#pragma unroll
        for (int ni = 0; ni < 4; ++ni) acc[mi][ni] = (float4_t){0.f, 0.f, 0.f, 0.f};

    const unsigned short* src_base = xpre + (size_t)b * 8 * 66 * 66 * 32;

    // stage 4 rows x 66 cols x 32 ci = 1056 x 16B, linear (xpre pre-swizzled)
    auto stage = [&](int cb, int buf) {
        const unsigned short* s = src_base + ((size_t)cb * 66 + r0) * 2112;
        unsigned short* d = xs[buf];
#pragma unroll
        for (int k = 0; k < 4; ++k)
            gload_lds16(s + (size_t)(tid + k * 256) * 8, d + (size_t)(tid + k * 256) * 8);
        if (tid < 32)
            gload_lds16(s + (size_t)(tid + 1024) * 8, d + (size_t)(tid + 1024) * 8);
    };

    short8_t abuf[3][4];
    auto loadA = [&](short8_t* dst, int acb, int atap) {
        const unsigned short* Ab = dwA + ((size_t)(b * 9 + atap) * 32 + acb * 4 + quad) * 2048
                                       + (size_t)(co_base + l16) * 8;
#pragma unroll
        for (int mi = 0; mi < 4; ++mi)
            dst[mi] = *(const short8_t*)(Ab + mi * 128);
    };

    short8_t bf[2][4];
    auto readB = [&](short8_t* dst, const unsigned short* xb, int tap) {
        const int dh = tap / 3, dwc = tap % 3;
        const unsigned short* brow = xb + (wave_n + dh) * (66 * 32);
#pragma unroll
        for (int ni = 0; ni < 4; ++ni) {
            const int col = ni * 16 + l16 + dwc;
            dst[ni] = *(const short8_t*)(brow + col * 32 + (quad ^ ((col >> 1) & 3)) * 8);
        }
    };

    stage(0, 0);
    loadA(abuf[0], 0, 0);
    loadA(abuf[1], 0, 1);

    for (int cb = 0; cb < 8; ++cb) {
        __syncthreads();                 // own-wave vmcnt(0) + barrier: xs[cb&1] ready
        if (cb < 7) stage(cb + 1, (cb + 1) & 1);

        const unsigned short* xb = xs[cb & 1];
        readB(bf[0], xb, 0);
#pragma unroll
        for (int tap = 0; tap < 9; ++tap) {
            // A prefetch two taps ahead (linearized across cb boundary):
            // global linear index L = cb*9 + tap consumes abuf[L%3] == abuf[tap%3]
            const int nl = tap + 2;
            const int acb = cb + nl / 9, atap = nl % 9;
            if (acb < 8) loadA(abuf[nl % 3], acb, atap);
            // B prefetch one tap ahead
            if (tap < 8) readB(bf[(tap + 1) & 1], xb, tap + 1);

            const short8_t* ac = abuf[tap % 3];
            const short8_t* bc = bf[tap & 1];
            __builtin_amdgcn_s_setprio(1);
#pragma unroll
            for (int mi = 0; mi < 4; ++mi)
#pragma unroll
                for (int ni = 0; ni < 4; ++ni)
                    acc[mi][ni] = __builtin_amdgcn_mfma_f32_16x16x32_bf16(
                        ac[mi], bc[ni], acc[mi][ni], 0, 0, 0);
            __builtin_amdgcn_s_setprio(0);
        }
    }

    // epilogue: D row = quad*4 + r (co), col = l16 (img col)
    const int orow = r0 + wave_n;
#pragma unroll
    for (int mi = 0; mi < 4; ++mi)
#pragma unroll
        for (int ni = 0; ni < 4; ++ni)
#pragma unroll
            for (int r = 0; r < 4; ++r) {
                int co = co_base + mi * 16 + quad * 4 + r;
                int c = ni * 16 + l16;
                out[(((size_t)b * COUT_ + co) * 64 + (size_t)orow) * 64 + c] = acc[mi][ni][r];
            }
}

extern "C" void kernel_launch(void* const* d_in, const int* in_sizes, int n_in,
                              void* d_out, int out_size, void* d_ws, size_t ws_size,
                              hipStream_t stream) {
    const float* x = (const float*)d_in[0];
    const float* style = (const float*)d_in[1];
    const float* weight = (const float*)d_in[2];
    float* out = (float*)d_out;

    unsigned short* dwA = (unsigned short*)d_ws;
    unsigned short* xpre = dwA + DWA_SHORTS;

    // blocks 0..63 modulate, 64..4287 xpre (64 + 8*8*66)
    k_prep<<<dim3(64 + B_ * 8 * 66), 256, 0, stream>>>(x, style, weight, xpre, dwA);
    // x = b so XCD (= linear_id % 8) = b: per-XCD dwA (1.18 MB) + xpre slice L2-resident
    k_conv<<<dim3(8, 32, 2), 256, 0, stream>>>(xpre, dwA, out);
}